// Round 14
// baseline (187.479 us; speedup 1.0000x reference)
//
#include <hip/hip_runtime.h>
#include <cstdint>
#include <cstddef>

#define EPS 1e-5f

typedef float    f4    __attribute__((ext_vector_type(4)));
typedef _Float16 half8 __attribute__((ext_vector_type(8)));
typedef _Float16 half4 __attribute__((ext_vector_type(4)));

#define S_XS 33
#define LOG2E 1.44269504088896f

#define GLD_LDS16(gp, lp)                                        \
    __builtin_amdgcn_global_load_lds(                            \
        (const __attribute__((address_space(1))) void*)(gp),     \
        (__attribute__((address_space(3))) void*)(lp), 16, 0, 0)

// raw-rate transcendentals (v_exp_f32 / v_rcp_f32 / v_rsq_f32)
__device__ __forceinline__ float fexp(float x)  { return __builtin_amdgcn_exp2f(x * LOG2E); }
__device__ __forceinline__ float frcp(float x)  { return __builtin_amdgcn_rcpf(x); }
__device__ __forceinline__ float frsq(float x)  { return __builtin_amdgcn_rsqf(x); }
__device__ __forceinline__ float fsig(float g)  { return frcp(1.f + __builtin_amdgcn_exp2f(g * -LOG2E)); }
__device__ __forceinline__ float felu(float t)  { return t > 0.f ? t : fexp(t) - 1.f; }

// ---- K_prep: conv (0..511) + weight-GRN (512..767) + out-zero (768..783) ----
// conv: f_fc2_w fp32 -> fp16, chunk layout [f][kq][q][g][j8] (16 KB per (f,kq)).
__global__ __launch_bounds__(256) void k_prep(
    const float* __restrict__ in_w2, _Float16* __restrict__ w2c,
    const float* __restrict__ x, const float* __restrict__ w1,
    const float* __restrict__ b1, const float* __restrict__ w2,
    const float* __restrict__ b2, const float* __restrict__ lng,
    const float* __restrict__ lnb,
    float* __restrict__ x_t, float* __restrict__ wts_t,
    float* __restrict__ outp)
{
    __shared__ float w1s[32 * S_XS];
    __shared__ float w2s[64 * S_XS];
    __shared__ float xsW[32 * S_XS];
    __shared__ float ytile[32 * S_XS];

    const int bid = blockIdx.x;
    const int tid = threadIdx.x;

    if (bid < 512) {   // ---- conv path ----
        int t = bid * 256 + tid;
        int q  = t & 3;
        int g  = (t >> 2) & 255;
        int fk = t >> 10;                   // f*4 + kq
        int f = fk >> 2, kq = fk & 3;
        const float* ip = in_w2 + ((size_t)f * 256 + g) * 128 + kq * 32 + q * 8;
        f4 v0 = *(const f4*)ip, v1 = *(const f4*)(ip + 4);
        half8 h;
        #pragma unroll
        for (int i = 0; i < 4; ++i) { h[i] = (_Float16)v0[i]; h[4 + i] = (_Float16)v1[i]; }
        *(half8*)(w2c + (size_t)fk * 8192 + q * 2048 + g * 8) = h;
        return;
    }

    if (bid >= 768) {  // ---- out-zero path (replaces memset launch) ----
        int t = (bid - 768) * 256 + tid;
        f4 z; z[0] = 0.f; z[1] = 0.f; z[2] = 0.f; z[3] = 0.f;
        for (int i = t; i < 262144; i += 4096)
            *(f4*)(outp + (size_t)i * 4) = z;
        return;
    }

    // ---- weight-GRN path ----
    const int lane = tid & 63;
    const int f = lane & 31;
    const int wv = tid >> 6;
    const int row0 = (bid - 512) * 32;

    for (int i = tid; i < 1024; i += 256) {
        int r = i >> 5, c = i & 31;
        w1s[r * S_XS + c] = w1[i];
        xsW[r * S_XS + c] = x[(size_t)row0 * 32 + i];
    }
    for (int i = tid; i < 2048; i += 256) {
        int r = i >> 5, c = i & 31;
        w2s[r * S_XS + c] = w2[i];
    }
    const float b1f = b1[f], b2a = b2[f], b2g = b2[f + 32];
    const float lgf = lng[f], lbf = lnb[f];
    __syncthreads();

    for (int rr = 0; rr < 8; ++rr) {
        const int r = wv * 8 + rr;
        float acc = b1f;
        #pragma unroll
        for (int k = 0; k < 32; ++k)
            acc = fmaf(w1s[f * S_XS + k], xsW[r * S_XS + k], acc);
        float hval = felu(acc);

        float a = b2a, g = b2g;
        #pragma unroll
        for (int k = 0; k < 32; ++k) {
            float hk = __shfl(hval, k, 64);
            a = fmaf(w2s[f * S_XS + k], hk, a);
            g = fmaf(w2s[(f + 32) * S_XS + k], hk, g);
        }
        float xv = xsW[r * S_XS + f];
        float v = xv + a * fsig(g);

        float s = v;
        #pragma unroll
        for (int o = 1; o < 64; o <<= 1) s += __shfl_xor(s, o, 64);
        float mu = s * (1.f / 64.f);
        float d = v - mu;
        float sq = d * d;
        #pragma unroll
        for (int o = 1; o < 64; o <<= 1) sq += __shfl_xor(sq, o, 64);
        float y = d * frsq(sq * (1.f / 64.f) + EPS) * lgf + lbf;

        float m = y;
        #pragma unroll
        for (int o = 1; o < 64; o <<= 1) m = fmaxf(m, __shfl_xor(m, o, 64));
        float e = fexp(y - m);
        float se = e;
        #pragma unroll
        for (int o = 1; o < 64; o <<= 1) se += __shfl_xor(se, o, 64);
        if (lane < 32) ytile[r * S_XS + f] = e * 2.f * frcp(se);
    }
    __syncthreads();
    for (int i = tid; i < 1024; i += 256) {
        int ff = i >> 5, r = i & 31;
        x_t[(size_t)ff * 8192 + row0 + r]   = xsW[r * S_XS + ff];
        wts_t[(size_t)ff * 8192 + row0 + r] = ytile[r * S_XS + ff];
    }
}

// ---------------- K_main: round-12 base + 32-KB phase merge (single delta) ----
// Block = 64 rows x 4 features; wave wv owns rows [16wv,16wv+16) x all 256 g.
// Phase = 2 chunks (32 KB), dbuf 2x32 KB -> 8 barriers/block (round 12: 16).
// Next-f staging issues BEFORE the epilogue -> stage latency overlaps epilogue
// VALU. Everything else (A-hoist, bias-fold, epilogue, atomics) = round-12
// verbatim (proven). Phase-merge exonerated: rounds 10/11 failed identically
// with AND without it (ep table was the bug). VGPR unchanged (~84) -> no spill.
__global__ __launch_bounds__(256, 3) void k_main(
    const _Float16* __restrict__ w2c,   // [32][4][4][256][8] fp16 chunks
    const float* __restrict__ x_t,      // [32][8192]
    const float* __restrict__ wts_t,    // [32][8192]
    const float* __restrict__ fc1w, const float* __restrict__ fc1b,
    const float* __restrict__ fc2b,
    const float* __restrict__ skw, const float* __restrict__ skb,
    const float* __restrict__ lng, const float* __restrict__ lnb,
    float* __restrict__ out)            // [8192][128], zeroed by k_prep
{
    __shared__ __align__(16) _Float16 bbuf[2][16384];   // 64 KB total

    const int tid = threadIdx.x;
    const int fbase = (blockIdx.x >> 7) * 4;
    const int row0 = (blockIdx.x & 127) * 64;

    const int lane = tid & 63;
    const int wv = tid >> 6;
    const int l15 = lane & 15;
    const int q = lane >> 4;
    const int boff = q * 2048 + l15 * 8;   // swizzled B-frag base within a chunk

    // stage phase ph: f = fbase + (ph>>1), chunks kq = (ph&1)*2 .. +1 (32 KB)
    auto stage = [&](int ph) {
        const _Float16* gp = w2c + ((size_t)(fbase + (ph >> 1)) * 4 + (ph & 1) * 2) * 8192;
        _Float16* lp = bbuf[ph & 1];
        #pragma unroll
        for (int r = 0; r < 8; ++r)
            GLD_LDS16(gp + (r * 256 + tid) * 8, lp + (r * 256 + tid) * 8);
    };

    float out_acc[8][4];
    #pragma unroll
    for (int nt = 0; nt < 8; ++nt)
        #pragma unroll
        for (int rg = 0; rg < 4; ++rg) out_acc[nt][rg] = 0.f;

    stage(0);
    __syncthreads();   // phase-0 buffer resident

    for (int fi = 0; fi < 4; ++fi) {
        const int f = fbase + fi;
        const float* xcol = x_t + (size_t)f * 8192 + row0 + wv * 16;
        const float* wcol = wts_t + (size_t)f * 8192 + row0 + wv * 16;
        const float xvA = xcol[l15];

        // A-frags for all 4 kq at f-start (proven rounds 9/12)
        half8 A[4];
        #pragma unroll
        for (int kq = 0; kq < 4; ++kq) {
            const float* wp = fc1w + f * 128 + kq * 32 + 8 * q;
            const float* bp = fc1b + f * 128 + kq * 32 + 8 * q;
            f4 w0 = *(const f4*)wp, w1v = *(const f4*)(wp + 4);
            f4 b0 = *(const f4*)bp, b1v = *(const f4*)(bp + 4);
            #pragma unroll
            for (int j = 0; j < 4; ++j) {
                A[kq][j]     = (_Float16)felu(fmaf(xvA, w0[j], b0[j]));
                A[kq][4 + j] = (_Float16)felu(fmaf(xvA, w1v[j], b1v[j]));
            }
        }

        // bias-fold: acc init from ba/bg (proven rounds 9/12)
        f4 acc[16];
        #pragma unroll
        for (int nt = 0; nt < 8; ++nt) {
            const int h = nt * 16 + l15;
            float ba = fc2b[f * 256 + h];
            float bg = fc2b[f * 256 + 128 + h];
            #pragma unroll
            for (int rg = 0; rg < 4; ++rg) { acc[nt][rg] = ba; acc[nt + 8][rg] = bg; }
        }

        #pragma unroll
        for (int half = 0; half < 2; ++half) {
            const int ph = fi * 2 + half;
            if (ph + 1 < 8) stage(ph + 1);
            #pragma unroll
            for (int kqL = 0; kqL < 2; ++kqL) {
                const int kq = half * 2 + kqL;
                const _Float16* bb = &bbuf[ph & 1][kqL * 8192 + boff];
                #pragma unroll
                for (int nt = 0; nt < 16; ++nt) {
                    half8 B = *(const half8*)(bb + nt * 128);   // [q][g=nt*16+l15][j]
                    acc[nt] = __builtin_amdgcn_mfma_f32_16x16x32_f16(A[kq], B, acc[nt], 0, 0, 0);
                }
            }
            __syncthreads();   // phase ph consumed everywhere; stage(ph+1) drained
        }

        // ---- epilogue: round-12 verbatim ----
        f4 xr = *(const f4*)(xcol + 4 * q);
        f4 wr = *(const f4*)(wcol + 4 * q);
        float s[4] = {0.f, 0.f, 0.f, 0.f}, sq[4] = {0.f, 0.f, 0.f, 0.f};
        #pragma unroll
        for (int nt = 0; nt < 8; ++nt) {
            const int h = nt * 16 + l15;
            float sw = skw[f * 128 + h];
            float sb = skb[f * 128 + h];
            #pragma unroll
            for (int rg = 0; rg < 4; ++rg) {
                float a = acc[nt][rg];              // ba folded into init
                float g = acc[nt + 8][rg];          // bg folded into init
                float val = fmaf(xr[rg], sw, sb) + a * fsig(g);
                acc[nt][rg] = val;
                s[rg] += val;
                sq[rg] = fmaf(val, val, sq[rg]);
            }
        }
        #pragma unroll
        for (int o = 1; o < 16; o <<= 1) {
            #pragma unroll
            for (int rg = 0; rg < 4; ++rg) {
                s[rg] += __shfl_xor(s[rg], o, 64);
                sq[rg] += __shfl_xor(sq[rg], o, 64);
            }
        }
        float mu[4], c1[4];
        #pragma unroll
        for (int rg = 0; rg < 4; ++rg) {
            mu[rg] = s[rg] * (1.f / 128.f);
            float var = sq[rg] * (1.f / 128.f) - mu[rg] * mu[rg];
            c1[rg] = wr[rg] * frsq(fmaxf(var, 0.f) + EPS);
        }
        #pragma unroll
        for (int nt = 0; nt < 8; ++nt) {
            const int h = nt * 16 + l15;
            float lg = lng[f * 128 + h];
            float lb = lnb[f * 128 + h];
            #pragma unroll
            for (int rg = 0; rg < 4; ++rg) {
                float u = (acc[nt][rg] - mu[rg]) * c1[rg];
                out_acc[nt][rg] = fmaf(u, lg, fmaf(wr[rg], lb, out_acc[nt][rg]));
            }
        }
    }

    // ---- single atomic combine pass (8 partial adds per element total) ----
    #pragma unroll
    for (int nt = 0; nt < 8; ++nt) {
        #pragma unroll
        for (int rg = 0; rg < 4; ++rg) {
            const int r = row0 + wv * 16 + 4 * q + rg;
            atomicAdd(&out[(size_t)r * 128 + nt * 16 + l15], out_acc[nt][rg]);
        }
    }
}

extern "C" void kernel_launch(void* const* d_in, const int* in_sizes, int n_in,
                              void* d_out, int out_size, void* d_ws, size_t ws_size,
                              hipStream_t stream) {
    const float* x     = (const float*)d_in[0];
    const float* wg1w  = (const float*)d_in[1];
    const float* wg1b  = (const float*)d_in[2];
    const float* wg2w  = (const float*)d_in[3];
    const float* wg2b  = (const float*)d_in[4];
    const float* wglng = (const float*)d_in[5];
    const float* wglnb = (const float*)d_in[6];
    const float* fc1w  = (const float*)d_in[7];
    const float* fc1b  = (const float*)d_in[8];
    const float* fc2w  = (const float*)d_in[9];
    const float* fc2b  = (const float*)d_in[10];
    const float* skw   = (const float*)d_in[11];
    const float* skb   = (const float*)d_in[12];
    const float* lng   = (const float*)d_in[13];
    const float* lnb   = (const float*)d_in[14];
    float* out = (float*)d_out;

    char* ws = (char*)d_ws;
    _Float16* w2c = (_Float16*)ws;               // 2 MB chunked fp16 W2
    float* x_t    = (float*)(ws + (2u << 20));   // 1 MB x transposed [f][row]
    float* wts_t  = (float*)(ws + (3u << 20));   // 1 MB weights transposed

    k_prep<<<dim3(784), dim3(256), 0, stream>>>(fc2w, w2c, x, wg1w, wg1b,
                                                wg2w, wg2b, wglng, wglnb,
                                                x_t, wts_t, out);
    k_main<<<dim3(1024), dim3(256), 0, stream>>>(w2c, x_t, wts_t, fc1w, fc1b,
                                                 fc2b, skw, skb, lng, lnb, out);
}

// Round 15
// 164.452 us; speedup vs baseline: 1.1400x; 1.1400x over previous
//
#include <hip/hip_runtime.h>
#include <cstdint>
#include <cstddef>

#define EPS 1e-5f

typedef float    f4    __attribute__((ext_vector_type(4)));
typedef _Float16 half8 __attribute__((ext_vector_type(8)));
typedef _Float16 half4 __attribute__((ext_vector_type(4)));

#define S_XS 33
#define LOG2E 1.44269504088896f

#define GLD_LDS16(gp, lp)                                        \
    __builtin_amdgcn_global_load_lds(                            \
        (const __attribute__((address_space(1))) void*)(gp),     \
        (__attribute__((address_space(3))) void*)(lp), 16, 0, 0)

// raw-rate transcendentals (v_exp_f32 / v_rcp_f32 / v_rsq_f32)
__device__ __forceinline__ float fexp(float x)  { return __builtin_amdgcn_exp2f(x * LOG2E); }
__device__ __forceinline__ float frcp(float x)  { return __builtin_amdgcn_rcpf(x); }
__device__ __forceinline__ float frsq(float x)  { return __builtin_amdgcn_rsqf(x); }
__device__ __forceinline__ float fsig(float g)  { return frcp(1.f + __builtin_amdgcn_exp2f(g * -LOG2E)); }
__device__ __forceinline__ float felu(float t)  { return t > 0.f ? t : fexp(t) - 1.f; }

// ---- K_prep: conv (0..511) + weight-GRN (512..767) + out-zero (768..783) ----
// conv: f_fc2_w fp32 -> fp16, chunk layout [f][kq][q][g][j8] (16 KB per (f,kq)).
// out-zero path (proven rounds 13/14) replaces the hipMemsetAsync dispatch.
__global__ __launch_bounds__(256) void k_prep(
    const float* __restrict__ in_w2, _Float16* __restrict__ w2c,
    const float* __restrict__ x, const float* __restrict__ w1,
    const float* __restrict__ b1, const float* __restrict__ w2,
    const float* __restrict__ b2, const float* __restrict__ lng,
    const float* __restrict__ lnb,
    float* __restrict__ x_t, float* __restrict__ wts_t,
    float* __restrict__ outp)
{
    __shared__ float w1s[32 * S_XS];
    __shared__ float w2s[64 * S_XS];
    __shared__ float xsW[32 * S_XS];
    __shared__ float ytile[32 * S_XS];

    const int bid = blockIdx.x;
    const int tid = threadIdx.x;

    if (bid < 512) {   // ---- conv path ----
        int t = bid * 256 + tid;
        int q  = t & 3;
        int g  = (t >> 2) & 255;
        int fk = t >> 10;                   // f*4 + kq
        int f = fk >> 2, kq = fk & 3;
        const float* ip = in_w2 + ((size_t)f * 256 + g) * 128 + kq * 32 + q * 8;
        f4 v0 = *(const f4*)ip, v1 = *(const f4*)(ip + 4);
        half8 h;
        #pragma unroll
        for (int i = 0; i < 4; ++i) { h[i] = (_Float16)v0[i]; h[4 + i] = (_Float16)v1[i]; }
        *(half8*)(w2c + (size_t)fk * 8192 + q * 2048 + g * 8) = h;
        return;
    }

    if (bid >= 768) {  // ---- out-zero path (replaces memset launch) ----
        int t = (bid - 768) * 256 + tid;
        f4 z; z[0] = 0.f; z[1] = 0.f; z[2] = 0.f; z[3] = 0.f;
        for (int i = t; i < 262144; i += 4096)
            *(f4*)(outp + (size_t)i * 4) = z;
        return;
    }

    // ---- weight-GRN path ----
    const int lane = tid & 63;
    const int f = lane & 31;
    const int wv = tid >> 6;
    const int row0 = (bid - 512) * 32;

    for (int i = tid; i < 1024; i += 256) {
        int r = i >> 5, c = i & 31;
        w1s[r * S_XS + c] = w1[i];
        xsW[r * S_XS + c] = x[(size_t)row0 * 32 + i];
    }
    for (int i = tid; i < 2048; i += 256) {
        int r = i >> 5, c = i & 31;
        w2s[r * S_XS + c] = w2[i];
    }
    const float b1f = b1[f], b2a = b2[f], b2g = b2[f + 32];
    const float lgf = lng[f], lbf = lnb[f];
    __syncthreads();

    for (int rr = 0; rr < 8; ++rr) {
        const int r = wv * 8 + rr;
        float acc = b1f;
        #pragma unroll
        for (int k = 0; k < 32; ++k)
            acc = fmaf(w1s[f * S_XS + k], xsW[r * S_XS + k], acc);
        float hval = felu(acc);

        float a = b2a, g = b2g;
        #pragma unroll
        for (int k = 0; k < 32; ++k) {
            float hk = __shfl(hval, k, 64);
            a = fmaf(w2s[f * S_XS + k], hk, a);
            g = fmaf(w2s[(f + 32) * S_XS + k], hk, g);
        }
        float xv = xsW[r * S_XS + f];
        float v = xv + a * fsig(g);

        float s = v;
        #pragma unroll
        for (int o = 1; o < 64; o <<= 1) s += __shfl_xor(s, o, 64);
        float mu = s * (1.f / 64.f);
        float d = v - mu;
        float sq = d * d;
        #pragma unroll
        for (int o = 1; o < 64; o <<= 1) sq += __shfl_xor(sq, o, 64);
        float y = d * frsq(sq * (1.f / 64.f) + EPS) * lgf + lbf;

        float m = y;
        #pragma unroll
        for (int o = 1; o < 64; o <<= 1) m = fmaxf(m, __shfl_xor(m, o, 64));
        float e = fexp(y - m);
        float se = e;
        #pragma unroll
        for (int o = 1; o < 64; o <<= 1) se += __shfl_xor(se, o, 64);
        if (lane < 32) ytile[r * S_XS + f] = e * 2.f * frcp(se);
    }
    __syncthreads();
    for (int i = tid; i < 1024; i += 256) {
        int ff = i >> 5, r = i & 31;
        x_t[(size_t)ff * 8192 + row0 + r]   = xsW[r * S_XS + ff];
        wts_t[(size_t)ff * 8192 + row0 + r] = ytile[r * S_XS + ff];
    }
}

// ---------------- K_main: round-12 verbatim (proven optimum of this structure) ----
// Block = 64 rows x 4 features; wave wv owns rows [16wv,16wv+16) x all 256 g.
// 16-KB chunk staging, dbuf, 16 barriers; A-frags hoisted to f-start; ba/bg
// folded into acc init; in-wave LN; register out_acc; one atomic pass.
// Operating point (hard-won): 32 KB LDS + VGPR 84 (+64 AGPR acc) -> 3 waves/
// SIMD; round 13 (more rows/wave) spilled, round 14 (bigger LDS phase) halved
// occupancy — both regressed. Do not deviate without counter evidence.
__global__ __launch_bounds__(256, 3) void k_main(
    const _Float16* __restrict__ w2c,   // [32][4][4][256][8] fp16 chunks
    const float* __restrict__ x_t,      // [32][8192]
    const float* __restrict__ wts_t,    // [32][8192]
    const float* __restrict__ fc1w, const float* __restrict__ fc1b,
    const float* __restrict__ fc2b,
    const float* __restrict__ skw, const float* __restrict__ skb,
    const float* __restrict__ lng, const float* __restrict__ lnb,
    float* __restrict__ out)            // [8192][128], zeroed by k_prep
{
    __shared__ __align__(16) _Float16 bchunk[2][8192];   // 32 KB total

    const int tid = threadIdx.x;
    const int fbase = (blockIdx.x >> 7) * 4;
    const int row0 = (blockIdx.x & 127) * 64;

    const int lane = tid & 63;
    const int wv = tid >> 6;
    const int l15 = lane & 15;
    const int q = lane >> 4;
    const int boff = q * 2048 + l15 * 8;   // swizzled B-frag base (halves)

    auto stage = [&](int c) {
        const _Float16* gp = w2c + ((size_t)(fbase + (c >> 2)) * 4 + (c & 3)) * 8192;
        #pragma unroll
        for (int r = 0; r < 4; ++r)
            GLD_LDS16(gp + (r * 256 + tid) * 8,
                      &bchunk[c & 1][(r * 256 + tid) * 8]);
    };

    float out_acc[8][4];
    #pragma unroll
    for (int nt = 0; nt < 8; ++nt)
        #pragma unroll
        for (int rg = 0; rg < 4; ++rg) out_acc[nt][rg] = 0.f;

    stage(0);
    __syncthreads();   // chunk 0 resident

    int c = 0;
    for (int fi = 0; fi < 4; ++fi) {
        const int f = fbase + fi;
        const float* xcol = x_t + (size_t)f * 8192 + row0 + wv * 16;
        const float* wcol = wts_t + (size_t)f * 8192 + row0 + wv * 16;
        const float xvA = xcol[l15];

        // A-frags for all 4 kq at f-start (proven rounds 9/12)
        half8 A[4];
        #pragma unroll
        for (int kq = 0; kq < 4; ++kq) {
            const float* wp = fc1w + f * 128 + kq * 32 + 8 * q;
            const float* bp = fc1b + f * 128 + kq * 32 + 8 * q;
            f4 w0 = *(const f4*)wp, w1v = *(const f4*)(wp + 4);
            f4 b0 = *(const f4*)bp, b1v = *(const f4*)(bp + 4);
            #pragma unroll
            for (int j = 0; j < 4; ++j) {
                A[kq][j]     = (_Float16)felu(fmaf(xvA, w0[j], b0[j]));
                A[kq][4 + j] = (_Float16)felu(fmaf(xvA, w1v[j], b1v[j]));
            }
        }

        // bias-fold: acc init from ba/bg (proven rounds 9/12)
        f4 acc[16];
        #pragma unroll
        for (int nt = 0; nt < 8; ++nt) {
            const int h = nt * 16 + l15;
            float ba = fc2b[f * 256 + h];
            float bg = fc2b[f * 256 + 128 + h];
            #pragma unroll
            for (int rg = 0; rg < 4; ++rg) { acc[nt][rg] = ba; acc[nt + 8][rg] = bg; }
        }

        #pragma unroll
        for (int kq = 0; kq < 4; ++kq, ++c) {
            if (c + 1 < 16) stage(c + 1);
            const _Float16* bb = &bchunk[c & 1][boff];
            #pragma unroll
            for (int nt = 0; nt < 16; ++nt) {
                half8 B = *(const half8*)(bb + nt * 128);   // [q][g=nt*16+l15][j]
                acc[nt] = __builtin_amdgcn_mfma_f32_16x16x32_f16(A[kq], B, acc[nt], 0, 0, 0);
            }
            __syncthreads();   // chunk c consumed everywhere; stage(c+1) drained
        }

        // ---- epilogue: round-12 verbatim ----
        f4 xr = *(const f4*)(xcol + 4 * q);
        f4 wr = *(const f4*)(wcol + 4 * q);
        float s[4] = {0.f, 0.f, 0.f, 0.f}, sq[4] = {0.f, 0.f, 0.f, 0.f};
        #pragma unroll
        for (int nt = 0; nt < 8; ++nt) {
            const int h = nt * 16 + l15;
            float sw = skw[f * 128 + h];
            float sb = skb[f * 128 + h];
            #pragma unroll
            for (int rg = 0; rg < 4; ++rg) {
                float a = acc[nt][rg];              // ba folded into init
                float g = acc[nt + 8][rg];          // bg folded into init
                float val = fmaf(xr[rg], sw, sb) + a * fsig(g);
                acc[nt][rg] = val;
                s[rg] += val;
                sq[rg] = fmaf(val, val, sq[rg]);
            }
        }
        #pragma unroll
        for (int o = 1; o < 16; o <<= 1) {
            #pragma unroll
            for (int rg = 0; rg < 4; ++rg) {
                s[rg] += __shfl_xor(s[rg], o, 64);
                sq[rg] += __shfl_xor(sq[rg], o, 64);
            }
        }
        float mu[4], c1[4];
        #pragma unroll
        for (int rg = 0; rg < 4; ++rg) {
            mu[rg] = s[rg] * (1.f / 128.f);
            float var = sq[rg] * (1.f / 128.f) - mu[rg] * mu[rg];
            c1[rg] = wr[rg] * frsq(fmaxf(var, 0.f) + EPS);
        }
        #pragma unroll
        for (int nt = 0; nt < 8; ++nt) {
            const int h = nt * 16 + l15;
            float lg = lng[f * 128 + h];
            float lb = lnb[f * 128 + h];
            #pragma unroll
            for (int rg = 0; rg < 4; ++rg) {
                float u = (acc[nt][rg] - mu[rg]) * c1[rg];
                out_acc[nt][rg] = fmaf(u, lg, fmaf(wr[rg], lb, out_acc[nt][rg]));
            }
        }
    }

    // ---- single atomic combine pass (8 partial adds per element total) ----
    #pragma unroll
    for (int nt = 0; nt < 8; ++nt) {
        #pragma unroll
        for (int rg = 0; rg < 4; ++rg) {
            const int r = row0 + wv * 16 + 4 * q + rg;
            atomicAdd(&out[(size_t)r * 128 + nt * 16 + l15], out_acc[nt][rg]);
        }
    }
}

extern "C" void kernel_launch(void* const* d_in, const int* in_sizes, int n_in,
                              void* d_out, int out_size, void* d_ws, size_t ws_size,
                              hipStream_t stream) {
    const float* x     = (const float*)d_in[0];
    const float* wg1w  = (const float*)d_in[1];
    const float* wg1b  = (const float*)d_in[2];
    const float* wg2w  = (const float*)d_in[3];
    const float* wg2b  = (const float*)d_in[4];
    const float* wglng = (const float*)d_in[5];
    const float* wglnb = (const float*)d_in[6];
    const float* fc1w  = (const float*)d_in[7];
    const float* fc1b  = (const float*)d_in[8];
    const float* fc2w  = (const float*)d_in[9];
    const float* fc2b  = (const float*)d_in[10];
    const float* skw   = (const float*)d_in[11];
    const float* skb   = (const float*)d_in[12];
    const float* lng   = (const float*)d_in[13];
    const float* lnb   = (const float*)d_in[14];
    float* out = (float*)d_out;

    char* ws = (char*)d_ws;
    _Float16* w2c = (_Float16*)ws;               // 2 MB chunked fp16 W2
    float* x_t    = (float*)(ws + (2u << 20));   // 1 MB x transposed [f][row]
    float* wts_t  = (float*)(ws + (3u << 20));   // 1 MB weights transposed

    k_prep<<<dim3(784), dim3(256), 0, stream>>>(fc2w, w2c, x, wg1w, wg1b,
                                                wg2w, wg2b, wglng, wglnb,
                                                x_t, wts_t, out);
    k_main<<<dim3(1024), dim3(256), 0, stream>>>(w2c, x_t, wts_t, fc1w, fc1b,
                                                 fc2b, skw, skb, lng, lnb, out);
}